// Round 1
// baseline (331.497 us; speedup 1.0000x reference)
//
#include <hip/hip_runtime.h>
#include <math.h>

#define BETA 5.5f
#define NC 1000
#define NM 51
#define ND 1024

__device__ __forceinline__ float wave_reduce_sum(float v) {
#pragma unroll
    for (int off = 32; off >= 1; off >>= 1) v += __shfl_xor(v, off, 64);
    return v;
}

__device__ __forceinline__ float block_reduce_sum(float v, float* red, int w, int lane) {
    v = wave_reduce_sum(v);
    __syncthreads();               // protect red from previous use
    if (lane == 0) red[w] = v;
    __syncthreads();
    return red[0] + red[1] + red[2] + red[3];
}

// Kernel 1: column sums of global_bias (C x D) -> qsum[D] (pre-zeroed)
__global__ __launch_bounds__(128) void colsum_kernel(const float* __restrict__ gb,
                                                     float* __restrict__ qsum) {
    int d = blockIdx.x * 128 + threadIdx.x;       // 8 blocks x 128 = 1024
    int c0 = blockIdx.y * 125;                    // 8 blocks x 125 = 1000
    const float* p = gb + (size_t)c0 * ND + d;
    float s = 0.f;
    for (int c = 0; c < 125; ++c) s += p[(size_t)c * ND];
    atomicAdd(&qsum[d], s);
}

// Kernel 2: one block per class. 4 waves; wave w handles rows m = w, w+4, ...
__global__ __launch_bounds__(256) void dualmem_main(
    const float* __restrict__ img,
    const float* __restrict__ mem,     // (C,50,D)
    const float* __restrict__ fixedg,  // (C,1,D)
    const float* __restrict__ qsum,    // (D) colsums of global_bias
    const float* __restrict__ gbk,     // (C,D)
    const float* __restrict__ gbv,     // (C,D)
    const float* __restrict__ ffn,     // (C,D)
    const float* __restrict__ lsp,     // scalar
    float* __restrict__ logits)        // (C)
{
    __shared__ float lds_acc[4 * ND];  // 16 KB: per-wave adaptive partials
    __shared__ float red[8];

    const int c = blockIdx.x;
    const int t = threadIdx.x;
    const int w = t >> 6;
    const int lane = t & 63;

    // ---- qn = l2norm(img + qsum/C), each wave holds full vector (16 f/lane) ----
    float4 qn[4];
    float ssq = 0.f;
#pragma unroll
    for (int j = 0; j < 4; ++j) {
        float4 iv = ((const float4*)img)[j * 64 + lane];
        float4 sv = ((const float4*)qsum)[j * 64 + lane];
        float4 qv;
        qv.x = iv.x + sv.x * (1.f / NC);
        qv.y = iv.y + sv.y * (1.f / NC);
        qv.z = iv.z + sv.z * (1.f / NC);
        qv.w = iv.w + sv.w * (1.f / NC);
        ssq += qv.x * qv.x + qv.y * qv.y + qv.z * qv.z + qv.w * qv.w;
        qn[j] = qv;
    }
    ssq = wave_reduce_sum(ssq);
    float qrn = rsqrtf(ssq);
#pragma unroll
    for (int j = 0; j < 4; ++j) {
        qn[j].x *= qrn; qn[j].y *= qrn; qn[j].z *= qrn; qn[j].w *= qrn;
    }

    // ---- per-class biases ----
    const float* bkp = gbk + (size_t)c * ND;
    const float* bvp = gbv + (size_t)c * ND;
    float4 bk[4], bv[4], acc[4];
#pragma unroll
    for (int j = 0; j < 4; ++j) {
        bk[j] = ((const float4*)bkp)[j * 64 + lane];
        bv[j] = ((const float4*)bvp)[j * 64 + lane];
        acc[j] = make_float4(0.f, 0.f, 0.f, 0.f);
    }

    // ---- main loop over memory rows ----
    for (int m = w; m < NM; m += 4) {
        const float* row = (m < 50) ? mem + ((size_t)c * 50 + m) * ND
                                    : fixedg + (size_t)c * ND;
        float4 mv[4];
        float sm = 0.f, ssqK = 0.f, dotK = 0.f, ssqV = 0.f;
#pragma unroll
        for (int j = 0; j < 4; ++j) {
            float4 v = ((const float4*)row)[j * 64 + lane];
            mv[j] = v;
            sm += v.x + v.y + v.z + v.w;
            float kx = v.x + bk[j].x, ky = v.y + bk[j].y, kz = v.z + bk[j].z, kw = v.w + bk[j].w;
            ssqK += kx * kx + ky * ky + kz * kz + kw * kw;
            dotK += qn[j].x * kx + qn[j].y * ky + qn[j].z * kz + qn[j].w * kw;
            float vx = v.x + bv[j].x, vy = v.y + bv[j].y, vz = v.z + bv[j].z, vw = v.w + bv[j].w;
            ssqV += vx * vx + vy * vy + vz * vz + vw * vw;
        }
        sm   = wave_reduce_sum(sm);
        ssqK = wave_reduce_sum(ssqK);
        dotK = wave_reduce_sum(dotK);
        ssqV = wave_reduce_sum(ssqV);
        if (sm != 0.f) {  // non-empty slot
            float simv = expf(-BETA * (1.f - dotK * rsqrtf(ssqK)));
            float wt = simv * rsqrtf(ssqV);
#pragma unroll
            for (int j = 0; j < 4; ++j) {
                acc[j].x += wt * (mv[j].x + bv[j].x);
                acc[j].y += wt * (mv[j].y + bv[j].y);
                acc[j].z += wt * (mv[j].z + bv[j].z);
                acc[j].w += wt * (mv[j].w + bv[j].w);
            }
        }
    }

    // ---- combine per-wave accumulators through LDS ----
#pragma unroll
    for (int j = 0; j < 4; ++j)
        ((float4*)lds_acc)[w * 256 + j * 64 + lane] = acc[j];
    __syncthreads();

    float4 a = make_float4(0.f, 0.f, 0.f, 0.f);
#pragma unroll
    for (int wv = 0; wv < 4; ++wv) {
        float4 p = ((float4*)lds_acc)[wv * 256 + t];
        a.x += p.x; a.y += p.y; a.z += p.z; a.w += p.w;
    }

    // adaptive = l2norm(adaptive); adaptive = l2norm(adaptive + ffn[c])
    float ssqA = block_reduce_sum(a.x * a.x + a.y * a.y + a.z * a.z + a.w * a.w, red, w, lane);
    float arn = rsqrtf(ssqA);
    float4 fv = ((const float4*)(ffn + (size_t)c * ND))[t];
    a.x = a.x * arn + fv.x;
    a.y = a.y * arn + fv.y;
    a.z = a.z * arn + fv.z;
    a.w = a.w * arn + fv.w;
    float ssqB = block_reduce_sum(a.x * a.x + a.y * a.y + a.z * a.z + a.w * a.w, red, w, lane);
    float brn = rsqrtf(ssqB);

    // logit = exp(logit_scale) * <a/||a||, img>
    float4 iv = ((const float4*)img)[t];
    float dp = a.x * iv.x + a.y * iv.y + a.z * iv.z + a.w * iv.w;
    dp = block_reduce_sum(dp, red, w, lane);

    if (t == 0) logits[c] = expf(lsp[0]) * dp * brn;
}

// Kernel 3: softmax over 1000 logits
__global__ __launch_bounds__(256) void softmax_kernel(const float* __restrict__ logits,
                                                      float* __restrict__ out) {
    __shared__ float red[8];
    int t = threadIdx.x, w = t >> 6, lane = t & 63;
    float l[4];
#pragma unroll
    for (int i = 0; i < 4; ++i) {
        int idx = t * 4 + i;
        l[i] = (idx < NC) ? logits[idx] : -3.402823466e+38f;
    }
    float mx = fmaxf(fmaxf(l[0], l[1]), fmaxf(l[2], l[3]));
#pragma unroll
    for (int off = 32; off >= 1; off >>= 1) mx = fmaxf(mx, __shfl_xor(mx, off, 64));
    __syncthreads();
    if (lane == 0) red[w] = mx;
    __syncthreads();
    mx = fmaxf(fmaxf(red[0], red[1]), fmaxf(red[2], red[3]));
    __syncthreads();

    float e[4], s = 0.f;
#pragma unroll
    for (int i = 0; i < 4; ++i) {
        int idx = t * 4 + i;
        e[i] = (idx < NC) ? expf(l[i] - mx) : 0.f;
        s += e[i];
    }
    s = block_reduce_sum(s, red, w, lane);
    float inv = 1.f / s;
#pragma unroll
    for (int i = 0; i < 4; ++i) {
        int idx = t * 4 + i;
        if (idx < NC) out[idx] = e[i] * inv;
    }
}

extern "C" void kernel_launch(void* const* d_in, const int* in_sizes, int n_in,
                              void* d_out, int out_size, void* d_ws, size_t ws_size,
                              hipStream_t stream) {
    const float* img    = (const float*)d_in[0];  // (1,D)
    const float* mem    = (const float*)d_in[1];  // (C,50,D)
    const float* fixedg = (const float*)d_in[2];  // (C,1,D)
    const float* gb     = (const float*)d_in[3];  // (C,D)
    const float* gbk    = (const float*)d_in[4];  // (C,D)
    const float* gbv    = (const float*)d_in[5];  // (C,D)
    const float* ffn    = (const float*)d_in[6];  // (C,D)
    const float* ls     = (const float*)d_in[7];  // scalar

    float* ws     = (float*)d_ws;
    float* qsum   = ws;          // 1024 floats
    float* logits = ws + 1024;   // 1000 floats
    float* out    = (float*)d_out;

    hipMemsetAsync(qsum, 0, ND * sizeof(float), stream);
    colsum_kernel<<<dim3(8, 8), 128, 0, stream>>>(gb, qsum);
    dualmem_main<<<NC, 256, 0, stream>>>(img, mem, fixedg, qsum, gbk, gbv, ffn, ls, logits);
    softmax_kernel<<<1, 256, 0, stream>>>(logits, out);
}

// Round 3
// 317.582 us; speedup vs baseline: 1.0438x; 1.0438x over previous
//
#include <hip/hip_runtime.h>
#include <math.h>

#define BETA 5.5f
#define NC 1000
#define NM 51
#define ND 1024

typedef float nt_float4 __attribute__((ext_vector_type(4)));

__device__ __forceinline__ float wave_reduce_sum(float v) {
#pragma unroll
    for (int off = 32; off >= 1; off >>= 1) v += __shfl_xor(v, off, 64);
    return v;
}

__device__ __forceinline__ float block_reduce_sum(float v, float* red, int w, int lane) {
    v = wave_reduce_sum(v);
    __syncthreads();               // protect red from previous use
    if (lane == 0) red[w] = v;
    __syncthreads();
    return red[0] + red[1] + red[2] + red[3];
}

// Kernel 1: partial column sums of global_bias (C x D) -> qpart[8][D]
// grid (8,8): bx = d-chunk of 128, by = c-chunk of 125. Plain stores, no atomics.
__global__ __launch_bounds__(128) void colsum_kernel(const float* __restrict__ gb,
                                                     float* __restrict__ qpart) {
    int d = blockIdx.x * 128 + threadIdx.x;
    int c0 = blockIdx.y * 125;
    const float* p = gb + (size_t)c0 * ND + d;
    float s = 0.f;
    for (int c = 0; c < 125; ++c) s += p[(size_t)c * ND];
    qpart[blockIdx.y * ND + d] = s;
}

// Kernel 2: 2 blocks per class (grid=2000). Block handles rows ww, ww+8, ...
// where ww = (half*4 + wave). Writes 4KB partial adaptive vector per block.
__global__ __launch_bounds__(256) void dualmem_main(
    const float* __restrict__ img,
    const float* __restrict__ mem,     // (C,50,D)
    const float* __restrict__ fixedg,  // (C,1,D)
    const float* __restrict__ qpart,   // (8,D) partial colsums of global_bias
    const float* __restrict__ gbk,     // (C,D)
    const float* __restrict__ gbv,     // (C,D)
    float* __restrict__ accpart)       // (2000,D)
{
    __shared__ float lds_acc[4 * ND];  // 16 KB per-wave partials

    const int c = blockIdx.x >> 1;
    const int half = blockIdx.x & 1;
    const int t = threadIdx.x;
    const int w = t >> 6;
    const int lane = t & 63;
    const int ww = half * 4 + w;       // global wave id within class, 0..7

    // ---- qn = l2norm(img + colsum(gb)/C), each wave holds full vector ----
    float4 qn[4];
    float ssq = 0.f;
#pragma unroll
    for (int j = 0; j < 4; ++j) {
        float4 sv = make_float4(0.f, 0.f, 0.f, 0.f);
#pragma unroll
        for (int p = 0; p < 8; ++p) {
            float4 pv = ((const float4*)qpart)[p * 256 + j * 64 + lane];
            sv.x += pv.x; sv.y += pv.y; sv.z += pv.z; sv.w += pv.w;
        }
        float4 iv = ((const float4*)img)[j * 64 + lane];
        float4 qv;
        qv.x = iv.x + sv.x * (1.f / NC);
        qv.y = iv.y + sv.y * (1.f / NC);
        qv.z = iv.z + sv.z * (1.f / NC);
        qv.w = iv.w + sv.w * (1.f / NC);
        ssq += qv.x * qv.x + qv.y * qv.y + qv.z * qv.z + qv.w * qv.w;
        qn[j] = qv;
    }
    ssq = wave_reduce_sum(ssq);
    float qrn = rsqrtf(ssq);
#pragma unroll
    for (int j = 0; j < 4; ++j) {
        qn[j].x *= qrn; qn[j].y *= qrn; qn[j].z *= qrn; qn[j].w *= qrn;
    }

    // ---- per-class biases ----
    const float* bkp = gbk + (size_t)c * ND;
    const float* bvp = gbv + (size_t)c * ND;
    float4 bk[4], bv[4], acc[4];
#pragma unroll
    for (int j = 0; j < 4; ++j) {
        bk[j] = ((const float4*)bkp)[j * 64 + lane];
        bv[j] = ((const float4*)bvp)[j * 64 + lane];
        acc[j] = make_float4(0.f, 0.f, 0.f, 0.f);
    }

    // ---- main loop: this wave handles rows ww, ww+8, ... ----
    for (int m = ww; m < NM; m += 8) {
        const nt_float4* row = (m < 50) ? (const nt_float4*)(mem + ((size_t)c * 50 + m) * ND)
                                        : (const nt_float4*)(fixedg + (size_t)c * ND);
        nt_float4 mv[4];
        float sm = 0.f, ssqK = 0.f, dotK = 0.f, ssqV = 0.f;
#pragma unroll
        for (int j = 0; j < 4; ++j) {
            nt_float4 v = __builtin_nontemporal_load(&row[j * 64 + lane]);
            mv[j] = v;
            sm += v.x + v.y + v.z + v.w;
            float kx = v.x + bk[j].x, ky = v.y + bk[j].y, kz = v.z + bk[j].z, kw = v.w + bk[j].w;
            ssqK += kx * kx + ky * ky + kz * kz + kw * kw;
            dotK += qn[j].x * kx + qn[j].y * ky + qn[j].z * kz + qn[j].w * kw;
            float vx = v.x + bv[j].x, vy = v.y + bv[j].y, vz = v.z + bv[j].z, vw = v.w + bv[j].w;
            ssqV += vx * vx + vy * vy + vz * vz + vw * vw;
        }
        sm   = wave_reduce_sum(sm);
        ssqK = wave_reduce_sum(ssqK);
        dotK = wave_reduce_sum(dotK);
        ssqV = wave_reduce_sum(ssqV);
        if (sm != 0.f) {  // non-empty slot
            float simv = expf(-BETA * (1.f - dotK * rsqrtf(ssqK)));
            float wt = simv * rsqrtf(ssqV);
#pragma unroll
            for (int j = 0; j < 4; ++j) {
                acc[j].x += wt * (mv[j].x + bv[j].x);
                acc[j].y += wt * (mv[j].y + bv[j].y);
                acc[j].z += wt * (mv[j].z + bv[j].z);
                acc[j].w += wt * (mv[j].w + bv[j].w);
            }
        }
    }

    // ---- combine 4 waves through LDS, store 4KB block partial ----
#pragma unroll
    for (int j = 0; j < 4; ++j)
        ((float4*)lds_acc)[w * 256 + j * 64 + lane] = acc[j];
    __syncthreads();

    float4 a = make_float4(0.f, 0.f, 0.f, 0.f);
#pragma unroll
    for (int wv = 0; wv < 4; ++wv) {
        float4 p = ((float4*)lds_acc)[wv * 256 + t];
        a.x += p.x; a.y += p.y; a.z += p.z; a.w += p.w;
    }
    ((float4*)(accpart + (size_t)blockIdx.x * ND))[t] = a;
}

// Kernel 3: per class, sum 2 partials, l2norm, +ffn, l2norm, logit.
__global__ __launch_bounds__(256) void finalize_kernel(
    const float* __restrict__ img,
    const float* __restrict__ accpart,  // (2000,D)
    const float* __restrict__ ffn,      // (C,D)
    const float* __restrict__ lsp,      // scalar
    float* __restrict__ logits)         // (C)
{
    __shared__ float red[8];
    const int c = blockIdx.x;
    const int t = threadIdx.x;
    const int w = t >> 6;
    const int lane = t & 63;

    float4 a0 = ((const float4*)(accpart + (size_t)(2 * c) * ND))[t];
    float4 a1 = ((const float4*)(accpart + (size_t)(2 * c + 1) * ND))[t];
    float4 a;
    a.x = a0.x + a1.x; a.y = a0.y + a1.y; a.z = a0.z + a1.z; a.w = a0.w + a1.w;

    float ssqA = block_reduce_sum(a.x * a.x + a.y * a.y + a.z * a.z + a.w * a.w, red, w, lane);
    float arn = rsqrtf(ssqA);
    float4 fv = ((const float4*)(ffn + (size_t)c * ND))[t];
    a.x = a.x * arn + fv.x;
    a.y = a.y * arn + fv.y;
    a.z = a.z * arn + fv.z;
    a.w = a.w * arn + fv.w;
    float ssqB = block_reduce_sum(a.x * a.x + a.y * a.y + a.z * a.z + a.w * a.w, red, w, lane);
    float brn = rsqrtf(ssqB);

    float4 iv = ((const float4*)img)[t];
    float dp = a.x * iv.x + a.y * iv.y + a.z * iv.z + a.w * iv.w;
    dp = block_reduce_sum(dp, red, w, lane);

    if (t == 0) logits[c] = expf(lsp[0]) * dp * brn;
}

// Kernel 4: softmax over 1000 logits
__global__ __launch_bounds__(256) void softmax_kernel(const float* __restrict__ logits,
                                                      float* __restrict__ out) {
    __shared__ float red[8];
    int t = threadIdx.x, w = t >> 6, lane = t & 63;
    float l[4];
#pragma unroll
    for (int i = 0; i < 4; ++i) {
        int idx = t * 4 + i;
        l[i] = (idx < NC) ? logits[idx] : -3.402823466e+38f;
    }
    float mx = fmaxf(fmaxf(l[0], l[1]), fmaxf(l[2], l[3]));
#pragma unroll
    for (int off = 32; off >= 1; off >>= 1) mx = fmaxf(mx, __shfl_xor(mx, off, 64));
    __syncthreads();
    if (lane == 0) red[w] = mx;
    __syncthreads();
    mx = fmaxf(fmaxf(red[0], red[1]), fmaxf(red[2], red[3]));
    __syncthreads();

    float e[4], s = 0.f;
#pragma unroll
    for (int i = 0; i < 4; ++i) {
        int idx = t * 4 + i;
        e[i] = (idx < NC) ? expf(l[i] - mx) : 0.f;
        s += e[i];
    }
    s = block_reduce_sum(s, red, w, lane);
    float inv = 1.f / s;
#pragma unroll
    for (int i = 0; i < 4; ++i) {
        int idx = t * 4 + i;
        if (idx < NC) out[idx] = e[i] * inv;
    }
}

extern "C" void kernel_launch(void* const* d_in, const int* in_sizes, int n_in,
                              void* d_out, int out_size, void* d_ws, size_t ws_size,
                              hipStream_t stream) {
    const float* img    = (const float*)d_in[0];  // (1,D)
    const float* mem    = (const float*)d_in[1];  // (C,50,D)
    const float* fixedg = (const float*)d_in[2];  // (C,1,D)
    const float* gb     = (const float*)d_in[3];  // (C,D)
    const float* gbk    = (const float*)d_in[4];  // (C,D)
    const float* gbv    = (const float*)d_in[5];  // (C,D)
    const float* ffn    = (const float*)d_in[6];  // (C,D)
    const float* ls     = (const float*)d_in[7];  // scalar

    float* ws      = (float*)d_ws;
    float* qpart   = ws;                  // 8*1024
    float* accpart = ws + 8 * ND;         // 2000*1024
    float* logits  = accpart + 2000 * ND; // 1000
    float* out     = (float*)d_out;

    colsum_kernel<<<dim3(8, 8), 128, 0, stream>>>(gb, qpart);
    dualmem_main<<<2 * NC, 256, 0, stream>>>(img, mem, fixedg, qpart, gbk, gbv, accpart);
    finalize_kernel<<<NC, 256, 0, stream>>>(img, accpart, ffn, ls, logits);
    softmax_kernel<<<1, 256, 0, stream>>>(logits, out);
}